// Round 1
// baseline (62.204 us; speedup 1.0000x reference)
//
#include <hip/hip_runtime.h>
#include <hip/hip_bf16.h>

typedef __bf16 bf16;
typedef __bf16 bf16x8 __attribute__((ext_vector_type(8)));
typedef __bf16 bf16x4 __attribute__((ext_vector_type(4)));
typedef float  f32x4  __attribute__((ext_vector_type(4)));

#define KDIM 512
#define MDIM 64
#define TDIM 4096
#define BN   128
#define BK   64

// LDS byte layout
#define SA_OFF   0        // text tile  [64][64]  bf16, swizzled: 8192 B
#define SB_OFF   8192     // audio tile [128][64] bf16, swizzled: 16384 B
#define INVT_OFF 24576    // 64 floats
#define INVA_OFF 24832    // 128 floats
#define LDS_BYTES 25344

__global__ __launch_bounds__(256, 2)
void expnegl2_fused_kernel(const float* __restrict__ audio,
                           const float* __restrict__ text,
                           float* __restrict__ out)
{
    __shared__ __attribute__((aligned(16))) unsigned char lds[LDS_BYTES];

    const int tid  = threadIdx.x;
    const int b    = blockIdx.y;
    const int t0   = blockIdx.x * BN;

    const int c4   = tid & 15;   // 16-byte column chunk within 64-col tile
    const int r0   = tid >> 4;   // 0..15 base row
    const int lane = tid & 63;
    const int wave = tid >> 6;

    const float* aBase = audio + ((size_t)b * TDIM + t0) * KDIM;
    const float* tBase = text  + (size_t)b * MDIM * KDIM;

    f32x4 acc[4][2];
    #pragma unroll
    for (int i = 0; i < 4; ++i)
        #pragma unroll
        for (int j = 0; j < 2; ++j)
            acc[i][j] = (f32x4){0.f, 0.f, 0.f, 0.f};

    float ssA[8], ssT[4];
    #pragma unroll
    for (int j = 0; j < 8; ++j) ssA[j] = 0.f;
    #pragma unroll
    for (int j = 0; j < 4; ++j) ssT[j] = 0.f;

    const int frow = lane & 15;  // MFMA fragment row/col within 16
    const int kgrp = lane >> 4;  // MFMA k-group (0..3)

    for (int k0 = 0; k0 < KDIM; k0 += BK) {
        __syncthreads();   // previous tile's MFMA readers done

        // ---- stage text tile [64][BK]: fp32 load -> sumsq -> bf16 -> LDS ----
        #pragma unroll
        for (int j = 0; j < 4; ++j) {
            const int row = j * 16 + r0;
            f32x4 v = *reinterpret_cast<const f32x4*>(tBase + (size_t)row * KDIM + k0 + c4 * 4);
            ssT[j] += v.x * v.x + v.y * v.y + v.z * v.z + v.w * v.w;
            bf16x4 q = { (bf16)v.x, (bf16)v.y, (bf16)v.z, (bf16)v.w };
            const int off = SA_OFF + row * 128 + ((c4 * 8) ^ ((row & 7) << 4));
            *reinterpret_cast<unsigned long long*>(lds + off) =
                __builtin_bit_cast(unsigned long long, q);
        }
        // ---- stage audio tile [BN][BK] ----
        #pragma unroll
        for (int j = 0; j < 8; ++j) {
            const int row = j * 16 + r0;
            f32x4 v = *reinterpret_cast<const f32x4*>(aBase + (size_t)row * KDIM + k0 + c4 * 4);
            ssA[j] += v.x * v.x + v.y * v.y + v.z * v.z + v.w * v.w;
            bf16x4 q = { (bf16)v.x, (bf16)v.y, (bf16)v.z, (bf16)v.w };
            const int off = SB_OFF + row * 128 + ((c4 * 8) ^ ((row & 7) << 4));
            *reinterpret_cast<unsigned long long*>(lds + off) =
                __builtin_bit_cast(unsigned long long, q);
        }
        __syncthreads();   // tile visible

        // ---- MFMA: acc[mi][ni] += text_frag[mi] * audio_frag[ni] ----
        #pragma unroll
        for (int kk = 0; kk < 2; ++kk) {
            const int kbyte = kk * 64 + kgrp * 16;
            bf16x8 afrag[4], bfrag[2];
            #pragma unroll
            for (int mi = 0; mi < 4; ++mi) {
                const int row = mi * 16 + frow;
                afrag[mi] = *reinterpret_cast<const bf16x8*>(
                    lds + SA_OFF + row * 128 + (kbyte ^ ((row & 7) << 4)));
            }
            #pragma unroll
            for (int ni = 0; ni < 2; ++ni) {
                const int trow = wave * 32 + ni * 16 + frow;
                bfrag[ni] = *reinterpret_cast<const bf16x8*>(
                    lds + SB_OFF + trow * 128 + (kbyte ^ ((trow & 7) << 4)));
            }
            #pragma unroll
            for (int mi = 0; mi < 4; ++mi)
                #pragma unroll
                for (int ni = 0; ni < 2; ++ni)
                    asm volatile("v_mfma_f32_16x16x32_bf16 %0, %1, %2, %0"
                                 : "+v"(acc[mi][ni])
                                 : "v"(afrag[mi]), "v"(bfrag[ni]));
        }
    }

    // ---- reduce sum-of-squares across the 16 lanes sharing a row ----
    #pragma unroll
    for (int j = 0; j < 4; ++j) {
        float s = ssT[j];
        s += __shfl_xor(s, 1); s += __shfl_xor(s, 2);
        s += __shfl_xor(s, 4); s += __shfl_xor(s, 8);
        ssT[j] = s;
    }
    #pragma unroll
    for (int j = 0; j < 8; ++j) {
        float s = ssA[j];
        s += __shfl_xor(s, 1); s += __shfl_xor(s, 2);
        s += __shfl_xor(s, 4); s += __shfl_xor(s, 8);
        ssA[j] = s;
    }
    float* invT = reinterpret_cast<float*>(lds + INVT_OFF);
    float* invA = reinterpret_cast<float*>(lds + INVA_OFF);
    if (c4 == 0) {
        #pragma unroll
        for (int j = 0; j < 4; ++j)
            invT[j * 16 + r0] = 1.f / fmaxf(sqrtf(ssT[j]), 1e-12f);
        #pragma unroll
        for (int j = 0; j < 8; ++j)
            invA[j * 16 + r0] = 1.f / fmaxf(sqrtf(ssA[j]), 1e-12f);
    }
    __syncthreads();

    // ---- epilogue: scale by inv-norms, exp(-sqrt(max(2-2*dot, eps))) ----
    // C/D layout (16x16x32): col = lane&15, row = (lane>>4)*4 + j  [m89-verified]
    float* obase = out + (size_t)b * MDIM * TDIM + t0;
    #pragma unroll
    for (int ni = 0; ni < 2; ++ni) {
        const int cl = wave * 32 + ni * 16 + frow;   // local col in [0,128)
        const float iA = invA[cl];
        #pragma unroll
        for (int mi = 0; mi < 4; ++mi) {
            #pragma unroll
            for (int j = 0; j < 4; ++j) {
                const int m = mi * 16 + kgrp * 4 + j;
                const float dotn = acc[mi][ni][j] * invT[m] * iA;
                const float d2 = fmaxf(2.f - 2.f * dotn, 1e-12f);
                obase[(size_t)m * TDIM + cl] = __expf(-sqrtf(d2));
            }
        }
    }
}

extern "C" void kernel_launch(void* const* d_in, const int* in_sizes, int n_in,
                              void* d_out, int out_size, void* d_ws, size_t ws_size,
                              hipStream_t stream) {
    const float* audio = (const float*)d_in[0];
    const float* text  = (const float*)d_in[1];
    float* out = (float*)d_out;

    const int B = in_sizes[0] / (TDIM * KDIM);   // 32
    dim3 grid(TDIM / BN, B);
    expnegl2_fused_kernel<<<grid, 256, 0, stream>>>(audio, text, out);
}